// Round 15
// baseline (67.827 us; speedup 1.0000x reference)
//
#include <hip/hip_runtime.h>

#define S_LEN 4096
#define DM    1024
#define NH    8
#define NKV   2
#define HDIM  128
#define WINSZ 256

typedef unsigned short u16;
typedef unsigned int u32;
typedef float f32x4 __attribute__((ext_vector_type(4)));
typedef short bf16x8 __attribute__((ext_vector_type(8)));

// ---------- workspace layout (bytes) ----------
static const size_t OFF_XB   = 0;          // x bf16 [4096][1024]            8388608
static const size_t OFF_WQKV = 8388608;    // Wq|Wk|Wv bf16 [1536][1024]     3145728
static const size_t OFF_WO   = 11534336;   // Wo bf16 [1024][1024]           2097152
static const size_t OFF_QH   = 13631488;   // q bf16 [8][4096][128]          8388608
static const size_t OFF_KH   = 22020096;   // k bf16 [2][4096][128]          2097152
static const size_t OFF_VT   = 24117248;   // v^T bf16 [2][128][4096]        2097152
static const size_t OFF_OB   = 26214400;   // attn out bf16 [4096][1024]     8388608

__device__ __forceinline__ u16 f2bf(float f) {
  union { float f; unsigned int u; } v; v.f = f;
  unsigned int u = v.u;
  u += 0x7fffu + ((u >> 16) & 1u);   // RNE
  return (u16)(u >> 16);
}

__device__ __forceinline__ void gload_lds16(const u16* g, u16* l) {
  __builtin_amdgcn_global_load_lds((const __attribute__((address_space(1))) void*)g,
                                   (__attribute__((address_space(3))) void*)l, 16, 0, 0);
}

// ---------------- prep: x|Wq|Wk|Wv f32 -> bf16 (Wo folded into attn) ----------------
__global__ __launch_bounds__(256) void prep_kernel(
    const float* __restrict__ x,  const float* __restrict__ wq,
    const float* __restrict__ wk, const float* __restrict__ wv,
    u16* __restrict__ xb, u16* __restrict__ wqkvb) {
  int i = blockIdx.x * 256 + threadIdx.x;       // one float4 per thread
  const float* src; u16* dst;
  if (i < 1048576)      { src = x  + (size_t)i * 4;               dst = xb + (size_t)i * 4; }
  else if (i < 1310720) { int j = i - 1048576; src = wq + (size_t)j*4; dst = wqkvb + (size_t)j*4; }
  else if (i < 1376256) { int j = i - 1310720; src = wk + (size_t)j*4; dst = wqkvb + 1048576 + (size_t)j*4; }
  else                  { int j = i - 1376256; src = wv + (size_t)j*4; dst = wqkvb + 1310720 + (size_t)j*4; }
  float4 v = *(const float4*)src;
  ushort4 o;
  o.x = f2bf(v.x); o.y = f2bf(v.y); o.z = f2bf(v.z); o.w = f2bf(v.w);
  *(ushort4*)dst = o;
}

// ---------------- QKV GEMM: 128x192 tile, 512 thr / 8 waves, 256 blocks (1/CU) ----------------
// Wave = 64x48 (4x3 frags). LDS 80KB dbuf. Per-element q/k scatter; v columns
// route through 48KB swizzled LDS (reuses Bs) then coalesced 64B transposed writes.
__global__ __launch_bounds__(512) void gemm_qkv(
    const u16* __restrict__ A, const u16* __restrict__ B,
    const float* __restrict__ b0, const float* __restrict__ b1, const float* __restrict__ b2,
    u16* __restrict__ qh, u16* __restrict__ kh, u16* __restrict__ vt) {
  __shared__ __align__(16) u16 As[2][128 * 64];    // 2 x 16 KB
  __shared__ __align__(16) u16 Bs[2][192 * 64];    // 2 x 24 KB (also 48KB v-transpose staging)
  const int tid = threadIdx.x;
  const int w = tid >> 6, l = tid & 63;
  const int lo16 = l & 15, hi4 = l >> 4;

  const int nwg = gridDim.x;              // 256, % 8 == 0
  const int lin = blockIdx.x;
  const int s = (lin & 7) * (nwg >> 3) + (lin >> 3);
  const int m0 = (s & 31) * 128;          // 32 m-tiles
  const int n0 = (s >> 5) * 192;          // 8 n-tiles

  const int wm = w >> 2, wn = w & 3;      // wave tile: rows wm*64, cols wn*48
  const int K = 1024;

  f32x4 acc[4][3] = {};

  const int lr = l >> 3;               // row within 8-row chunk
  const int sc8 = 8 * ((l & 7) ^ lr);  // pre-swizzled elem col within 64-wide row

  auto stage = [&](int buf, int kt) {
    #pragma unroll
    for (int it = 0; it < 5; ++it) {
      int c = w * 5 + it;                       // 40 chunks: 16 As + 24 Bs
      if (c < 16) {
        int row = c * 8 + lr;
        gload_lds16(A + (size_t)(m0 + row) * K + kt + sc8, &As[buf][c * 512]);
      } else {
        int cc = c - 16;
        int row = cc * 8 + lr;
        gload_lds16(B + (size_t)(n0 + row) * K + kt + sc8, &Bs[buf][cc * 512]);
      }
    }
  };

  stage(0, 0);
  __syncthreads();
  int buf = 0;
  const int rswz = (lo16 & 7) << 4;    // read-side XOR (row&7)<<4; rows = *+lo16
  for (int kt = 0; kt < K; kt += 64) {
    if (kt + 64 < K) stage(buf ^ 1, kt + 64);
    #pragma unroll
    for (int kk = 0; kk < 2; ++kk) {
      bf16x8 af[4], bfr[3];
      const int colb = (kk * 64 + hi4 * 16) ^ rswz;   // swizzled byte col in 128B row
      #pragma unroll
      for (int f = 0; f < 4; ++f)
        af[f] = *(const bf16x8*)((const char*)&As[buf][0] + (wm * 64 + f * 16 + lo16) * 128 + colb);
      #pragma unroll
      for (int fn = 0; fn < 3; ++fn)
        bfr[fn] = *(const bf16x8*)((const char*)&Bs[buf][0] + (wn * 48 + fn * 16 + lo16) * 128 + colb);
      #pragma unroll
      for (int fm = 0; fm < 4; ++fm)
        #pragma unroll
        for (int fn = 0; fn < 3; ++fn)
          acc[fm][fn] = __builtin_amdgcn_mfma_f32_16x16x32_bf16(af[fm], bfr[fn], acc[fm][fn], 0, 0, 0);
    }
    __syncthreads();
    buf ^= 1;
  }

  // epilogue: per-element q/k scatter; v cols -> swizzled LDS then transposed write
  int vstart = 1280 - n0; if (vstart < 0) vstart = 0;   // local col where v begins
  const int vcount = 192 - vstart;                      // >0 iff n0 >= 1152
  u16* vl = &Bs[0][0];                                  // 48KB staging

  #pragma unroll
  for (int fm = 0; fm < 4; ++fm)
    #pragma unroll
    for (int fn = 0; fn < 3; ++fn) {
      f32x4 c = acc[fm][fn];
      const int lcol = wn * 48 + fn * 16 + lo16;
      const int gcol = n0 + lcol;
      const int rowb = m0 + wm * 64 + fm * 16 + hi4 * 4;
      const int lrowb = wm * 64 + fm * 16 + hi4 * 4;
      float bias = (gcol < 1024) ? b0[gcol] : (gcol < 1280 ? b1[gcol - 1024] : b2[gcol - 1280]);
      #pragma unroll
      for (int j = 0; j < 4; ++j) {
        u16 hb = f2bf(c[j] + bias);
        if (gcol < 1024) {
          qh[((size_t)(gcol >> 7) * S_LEN + rowb + j) * HDIM + (gcol & 127)] = hb;
        } else if (gcol < 1280) {
          int cc = gcol - 1024;
          kh[((size_t)(cc >> 7) * S_LEN + rowb + j) * HDIM + (cc & 127)] = hb;
        } else {
          int ch = lcol - vstart;                       // 0..vcount-1
          int a = ch * 256 + (((lrowb + j) * 2) ^ ((ch & 7) << 4));
          *(u16*)((char*)vl + a) = hb;
        }
      }
    }
  if (vcount > 0) {
    __syncthreads();
    const int ch0 = tid >> 2, q4 = tid & 3;
    #pragma unroll
    for (int base = 0; base < 192; base += 128) {
      int ch = base + ch0;
      if (ch < vcount) {
        int cc = n0 + vstart + ch - 1280;               // global v channel
        u16* dst = vt + (size_t)cc * S_LEN + m0 + q4 * 32;
        const int swz = (ch & 7) << 4;
        #pragma unroll
        for (int u = 0; u < 4; ++u) {
          uint4 vv = *(const uint4*)((const char*)vl + ch * 256 + ((q4 * 64 + u * 16) ^ swz));
          *(uint4*)(dst + u * 8) = vv;
        }
      }
    }
  }
}

// ---------------- out-proj GEMM: 128x128 tile, 512 thr / 8 waves, 256 blocks (R14) ----------------
__global__ __launch_bounds__(512) void gemm_out(
    const u16* __restrict__ A, const u16* __restrict__ B,
    const float* __restrict__ b0, float* __restrict__ outf) {
  __shared__ __align__(16) u16 As[2][128 * 64];    // 2 x 16 KB
  __shared__ __align__(16) u16 Bs[2][128 * 64];    // 2 x 16 KB
  const int tid = threadIdx.x;
  const int w = tid >> 6, l = tid & 63;            // 8 waves
  const int lo16 = l & 15, hi4 = l >> 4;

  const int nwg = gridDim.x;              // 256, % 8 == 0
  const int lin = blockIdx.x;
  const int s = (lin & 7) * (nwg >> 3) + (lin >> 3);
  const int m0 = (s & 31) * 128;          // 32 m-tiles
  const int n0 = (s >> 5) * 128;          // 8 n-tiles

  const int wm = w >> 2, wn = w & 3;      // wave tile: rows wm*64, cols wn*32
  const int K = 1024;

  f32x4 acc[4][2] = {};

  const int lr = l >> 3;
  const int sc8 = 8 * ((l & 7) ^ lr);

  auto stage = [&](int buf, int kt) {
    #pragma unroll
    for (int it = 0; it < 4; ++it) {
      int c = w * 4 + it;                 // 32 chunks: 16 As + 16 Bs
      if (c < 16) {
        int row = c * 8 + lr;
        gload_lds16(A + (size_t)(m0 + row) * K + kt + sc8, &As[buf][c * 512]);
      } else {
        int cc = c - 16;
        int row = cc * 8 + lr;
        gload_lds16(B + (size_t)(n0 + row) * K + kt + sc8, &Bs[buf][cc * 512]);
      }
    }
  };

  stage(0, 0);
  __syncthreads();
  int buf = 0;
  const int rswz = (lo16 & 7) << 4;
  for (int kt = 0; kt < K; kt += 64) {
    if (kt + 64 < K) stage(buf ^ 1, kt + 64);
    #pragma unroll
    for (int kk = 0; kk < 2; ++kk) {
      bf16x8 af[4], bfr[2];
      const int colb = (kk * 64 + hi4 * 16) ^ rswz;
      #pragma unroll
      for (int f = 0; f < 4; ++f)
        af[f] = *(const bf16x8*)((const char*)&As[buf][0] + (wm * 64 + f * 16 + lo16) * 128 + colb);
      #pragma unroll
      for (int fn = 0; fn < 2; ++fn)
        bfr[fn] = *(const bf16x8*)((const char*)&Bs[buf][0] + (wn * 32 + fn * 16 + lo16) * 128 + colb);
      #pragma unroll
      for (int fm = 0; fm < 4; ++fm)
        #pragma unroll
        for (int fn = 0; fn < 2; ++fn)
          acc[fm][fn] = __builtin_amdgcn_mfma_f32_16x16x32_bf16(af[fm], bfr[fn], acc[fm][fn], 0, 0, 0);
    }
    __syncthreads();
    buf ^= 1;
  }

  #pragma unroll
  for (int fm = 0; fm < 4; ++fm)
    #pragma unroll
    for (int fn = 0; fn < 2; ++fn) {
      f32x4 c = acc[fm][fn];
      const int col  = n0 + wn * 32 + fn * 16 + lo16;
      const int rowb = m0 + wm * 64 + fm * 16 + hi4 * 4;
      float bias = b0[col];
      #pragma unroll
      for (int j = 0; j < 4; ++j)
        outf[(size_t)(rowb + j) * DM + col] = c[j] + bias;
    }
}

// ---------------- attention: burst-staged K/V, 3 barriers; Wo fold after barrier 3 (R14) ----------------
__global__ __launch_bounds__(512) void attn_kernel(
    const u16* __restrict__ qh, const u16* __restrict__ kh,
    const u16* __restrict__ vt, const float* __restrict__ sb_ptr,
    const float* __restrict__ wo, u16* __restrict__ wob,
    u16* __restrict__ ob) {
  __shared__ __align__(16) u16 kv_lds[5 * 8192];   // 80KB: K tiles, reused for V tiles
  __shared__ __align__(16) u16 p_lds[16384];       // 32KB
  const int lin = blockIdx.x;                    // 256 blocks
  const int sblk = (lin & 7) * 32 + (lin >> 3);  // XCD-chunked
  const int g  = sblk >> 7;                      // kv group 0..1
  const int qt = sblk & 127;                     // 0..127
  const int r0 = qt * 32;
  const int tid = threadIdx.x;
  const int w = tid >> 6, l = tid & 63;
  const int lo16 = l & 15, hi4 = l >> 4;
  const int h  = g * 4 + (w >> 1);               // head for this wave
  const int rw = r0 + (w & 1) * 16;              // first q-row for this wave
  const float sb = *sb_ptr;
  const float scale = 0.08838834764831845f;      // 1/sqrt(128)

  int lo = r0 - (WINSZ - 1); if (lo < 0) lo = 0;
  const int jt0 = lo >> 6;
  const int nt  = (r0 >> 6) - jt0 + 1;   // 1..5 (block-uniform)

  // ---- burst-stage all K tiles (issued first) ----
  #pragma unroll
  for (int t = 0; t < 5; ++t) {
    if (t < nt) {
      const int jt = jt0 + t;
      #pragma unroll
      for (int it = 0; it < 2; ++it) {
        int ch = w * 2 + it;                                   // 16 chunks/tile
        int r  = ch * 4 + (l >> 4);                            // K row 0..63
        int cb = ((l & 15) * 16) ^ ((r & 7) << 4);             // pre-swizzled col byte
        gload_lds16(kh + ((size_t)g * S_LEN + jt * 64 + r) * HDIM + (cb >> 1),
                    &kv_lds[t * 8192 + ch * 512]);
      }
    }
  }

  // Q fragments
  bf16x8 aq[4];
  {
    const u16* qbase = qh + ((size_t)h * S_LEN + rw + lo16) * HDIM + hi4 * 8;
    #pragma unroll
    for (int kk = 0; kk < 4; ++kk) aq[kk] = *(const bf16x8*)(qbase + kk * 32);
  }

  __syncthreads();                                 // barrier 1: K staged

  // ---- all QK^T (swapped operands: lane holds q=lo16 row) ----
  f32x4 sc[5][4];
  #pragma unroll
  for (int t = 0; t < 5; ++t)
    #pragma unroll
    for (int jn = 0; jn < 4; ++jn) sc[t][jn] = (f32x4){0.f, 0.f, 0.f, 0.f};
  #pragma unroll
  for (int t = 0; t < 5; ++t) {
    if (t < nt) {
      #pragma unroll
      for (int jn = 0; jn < 4; ++jn) {
        const int R = jn * 16 + lo16;
        #pragma unroll
        for (int kk = 0; kk < 4; ++kk) {
          int addr = t * 16384 + R * 256 + ((kk * 64 + hi4 * 16) ^ ((R & 7) << 4));
          bf16x8 bk = *(const bf16x8*)((const char*)kv_lds + addr);
          sc[t][jn] = __builtin_amdgcn_mfma_f32_16x16x32_bf16(bk, aq[kk], sc[t][jn], 0, 0, 0);
        }
      }
    }
  }

  // ---- scale + mask + row max (regs only) ----
  const int ig = rw + lo16;
  float pmax = -3e38f;
  #pragma unroll
  for (int t = 0; t < 5; ++t) {
    if (t < nt) {
      const int jt = jt0 + t;
      const bool edge = (jt * 64 + 63 > rw) || (jt * 64 < rw - 240);
      #pragma unroll
      for (int jn = 0; jn < 4; ++jn) {
        #pragma unroll
        for (int j = 0; j < 4; ++j) {
          float s2 = sc[t][jn][j] * scale;
          if (edge) {
            const int jg = jt * 64 + jn * 16 + hi4 * 4 + j;
            bool valid = (jg <= ig) && (jg > ig - WINSZ);
            s2 = valid ? s2 : -1e30f;
          }
          sc[t][jn][j] = s2;
          pmax = fmaxf(pmax, s2);
        }
      }
    }
  }
  pmax = fmaxf(pmax, __shfl_xor(pmax, 16, 64));
  pmax = fmaxf(pmax, __shfl_xor(pmax, 32, 64));
  const float m = fmaxf(pmax, sb);

  __syncthreads();                                 // barrier 2: all K reads done

  // ---- burst-issue all V tiles into the same region ----
  #pragma unroll
  for (int t = 0; t < 5; ++t) {
    if (t < nt) {
      const int jt = jt0 + t;
      #pragma unroll
      for (int it = 0; it < 2; ++it) {
        int ch = w * 2 + it;
        int r  = ch * 8 + (l >> 3);                            // V row (d) 0..127
        int cb = 16 * ((l & 7) ^ (l >> 3));                    // pre-swizzled col byte
        gload_lds16(vt + ((size_t)g * HDIM + r) * S_LEN + jt * 64 + (cb >> 1),
                    &kv_lds[t * 8192 + ch * 512]);
      }
    }
  }

  // ---- exp pass in registers (overlaps V burst) ----
  float rsum = 0.f;
  #pragma unroll
  for (int t = 0; t < 5; ++t) {
    if (t < nt) {
      #pragma unroll
      for (int jn = 0; jn < 4; ++jn) {
        #pragma unroll
        for (int j = 0; j < 4; ++j) {
          float p = __expf(sc[t][jn][j] - m);
          sc[t][jn][j] = p;
          rsum += p;
        }
      }
    }
  }
  rsum += __shfl_xor(rsum, 16, 64);
  rsum += __shfl_xor(rsum, 32, 64);

  __syncthreads();                                 // barrier 3: V staged

  // ---- fold: convert this block's Wo slice (no barrier after -> hides under PV) ----
  {
    const float* src = wo + (size_t)lin * 4096;
    u16* dst = wob + (size_t)lin * 4096;
    #pragma unroll
    for (int it = 0; it < 2; ++it) {
      int i = (it * 512 + tid) * 4;
      float4 v = *(const float4*)(src + i);
      ushort4 o;
      o.x = f2bf(v.x); o.y = f2bf(v.y); o.z = f2bf(v.z); o.w = f2bf(v.w);
      *(ushort4*)(dst + i) = o;
    }
  }

  // ---- all PV (P store -> 16 MFMA per tile; per-wave P slots, no barriers) ----
  f32x4 acc_o[8] = {};
  const int pswz = (lo16 & 7) << 4;
  #pragma unroll
  for (int t = 0; t < 5; ++t) {
    if (t < nt) {
      char* pw = (char*)p_lds + (w * 2 + (t & 1)) * 2048 + lo16 * 128;
      #pragma unroll
      for (int jn = 0; jn < 4; ++jn) {
        uint2 pk;
        pk.x = (u32)f2bf(sc[t][jn][0]) | ((u32)f2bf(sc[t][jn][1]) << 16);
        pk.y = (u32)f2bf(sc[t][jn][2]) | ((u32)f2bf(sc[t][jn][3]) << 16);
        *(uint2*)(pw + ((jn * 32 + hi4 * 8) ^ pswz)) = pk;
      }
      #pragma unroll
      for (int kkp = 0; kkp < 2; ++kkp) {
        bf16x8 ap = *(const bf16x8*)((const char*)p_lds + (w * 2 + (t & 1)) * 2048
                                     + lo16 * 128 + ((kkp * 64 + hi4 * 16) ^ pswz));
        #pragma unroll
        for (int dn = 0; dn < 8; ++dn) {
          const int R = dn * 16 + lo16;
          int va = t * 16384 + R * 128 + ((kkp * 64 + hi4 * 16) ^ ((R & 7) << 4));
          bf16x8 bv = *(const bf16x8*)((const char*)kv_lds + va);
          acc_o[dn] = __builtin_amdgcn_mfma_f32_16x16x32_bf16(ap, bv, acc_o[dn], 0, 0, 0);
        }
      }
    }
  }

  // ---- finalize ----
  const float invl = 1.f / (rsum + __expf(sb - m));
  float invj[4];
  #pragma unroll
  for (int j = 0; j < 4; ++j) invj[j] = __shfl(invl, hi4 * 4 + j, 64);
  #pragma unroll
  for (int dn = 0; dn < 8; ++dn)
    #pragma unroll
    for (int j = 0; j < 4; ++j)
      ob[(size_t)(rw + hi4 * 4 + j) * DM + h * HDIM + dn * 16 + lo16] = f2bf(acc_o[dn][j] * invj[j]);
}

extern "C" void kernel_launch(void* const* d_in, const int* in_sizes, int n_in,
                              void* d_out, int out_size, void* d_ws, size_t ws_size,
                              hipStream_t stream) {
  const float* x  = (const float*)d_in[0];
  const float* sb = (const float*)d_in[1];
  const float* wq = (const float*)d_in[2];
  const float* bq = (const float*)d_in[3];
  const float* wk = (const float*)d_in[4];
  const float* bk = (const float*)d_in[5];
  const float* wv = (const float*)d_in[6];
  const float* bv = (const float*)d_in[7];
  const float* wo = (const float*)d_in[8];
  const float* bo = (const float*)d_in[9];
  float* out = (float*)d_out;
  char* ws = (char*)d_ws;

  u16* xb    = (u16*)(ws + OFF_XB);
  u16* wqkvb = (u16*)(ws + OFF_WQKV);
  u16* wob   = (u16*)(ws + OFF_WO);
  u16* qh    = (u16*)(ws + OFF_QH);
  u16* kh    = (u16*)(ws + OFF_KH);
  u16* vt    = (u16*)(ws + OFF_VT);
  u16* ob    = (u16*)(ws + OFF_OB);

  // x|Wq|Wk|Wv: 1441792 float4s -> 5632 blocks
  prep_kernel<<<dim3(5632), dim3(256), 0, stream>>>(x, wq, wk, wv, xb, wqkvb);
  // qkv projection: M=4096, N=1536 -> 32 x 8 = 256 blocks, 128x192 tile, 512 thr
  gemm_qkv<<<dim3(256), dim3(512), 0, stream>>>(xb, wqkvb, bq, bk, bv, qh, kh, vt);
  // attention (+ Wo conversion fold): 256 blocks, 512 thr
  attn_kernel<<<dim3(256), dim3(512), 0, stream>>>(qh, kh, vt, sb, wo, wob, ob);
  // out projection: M=4096, N=1024 -> 256 blocks, 128^2 tile, 512 thr / 8 waves
  gemm_out<<<dim3(256), dim3(512), 0, stream>>>(ob, wob, bo, out);
}

// Round 16
// 65.691 us; speedup vs baseline: 1.0325x; 1.0325x over previous
//
#include <hip/hip_runtime.h>

#define S_LEN 4096
#define DM    1024
#define NH    8
#define NKV   2
#define HDIM  128
#define WINSZ 256

typedef unsigned short u16;
typedef unsigned int u32;
typedef float f32x4 __attribute__((ext_vector_type(4)));
typedef short bf16x8 __attribute__((ext_vector_type(8)));

// ---------- workspace layout (bytes) ----------
static const size_t OFF_XB   = 0;          // x bf16 [4096][1024]            8388608
static const size_t OFF_WQKV = 8388608;    // Wq|Wk|Wv bf16 [1536][1024]     3145728
static const size_t OFF_WO   = 11534336;   // Wo bf16 [1024][1024]           2097152
static const size_t OFF_QH   = 13631488;   // q bf16 [8][4096][128]          8388608
static const size_t OFF_KH   = 22020096;   // k bf16 [2][4096][128]          2097152
static const size_t OFF_VT   = 24117248;   // v^T bf16 [2][128][4096]        2097152
static const size_t OFF_OB   = 26214400;   // attn out bf16 [4096][1024]     8388608

__device__ __forceinline__ u16 f2bf(float f) {
  union { float f; unsigned int u; } v; v.f = f;
  unsigned int u = v.u;
  u += 0x7fffu + ((u >> 16) & 1u);   // RNE
  return (u16)(u >> 16);
}

__device__ __forceinline__ void gload_lds16(const u16* g, u16* l) {
  __builtin_amdgcn_global_load_lds((const __attribute__((address_space(1))) void*)g,
                                   (__attribute__((address_space(3))) void*)l, 16, 0, 0);
}

// ---------------- prep: x|Wq|Wk|Wv f32 -> bf16 (Wo folded into attn) ----------------
__global__ __launch_bounds__(256) void prep_kernel(
    const float* __restrict__ x,  const float* __restrict__ wq,
    const float* __restrict__ wk, const float* __restrict__ wv,
    u16* __restrict__ xb, u16* __restrict__ wqkvb) {
  int i = blockIdx.x * 256 + threadIdx.x;       // one float4 per thread
  const float* src; u16* dst;
  if (i < 1048576)      { src = x  + (size_t)i * 4;               dst = xb + (size_t)i * 4; }
  else if (i < 1310720) { int j = i - 1048576; src = wq + (size_t)j*4; dst = wqkvb + (size_t)j*4; }
  else if (i < 1376256) { int j = i - 1310720; src = wk + (size_t)j*4; dst = wqkvb + 1048576 + (size_t)j*4; }
  else                  { int j = i - 1376256; src = wv + (size_t)j*4; dst = wqkvb + 1310720 + (size_t)j*4; }
  float4 v = *(const float4*)src;
  ushort4 o;
  o.x = f2bf(v.x); o.y = f2bf(v.y); o.z = f2bf(v.z); o.w = f2bf(v.w);
  *(ushort4*)dst = o;
}

// ---------------- QKV GEMM, 128x128 tile, 384 blocks, 256 thr (R14 version) ----------------
__global__ __launch_bounds__(256) void gemm_qkv(
    const u16* __restrict__ A, const u16* __restrict__ B,
    const float* __restrict__ b0, const float* __restrict__ b1, const float* __restrict__ b2,
    u16* __restrict__ qh, u16* __restrict__ kh, u16* __restrict__ vt) {
  __shared__ __align__(16) u16 As[2][128 * 64];    // 2 x 16 KB
  __shared__ __align__(16) u16 Bs[2][128 * 64];    // 2 x 16 KB
  const int tid = threadIdx.x;
  const int w = tid >> 6, l = tid & 63;
  const int lo16 = l & 15, hi4 = l >> 4;

  const int nwg = gridDim.x;              // 384, % 8 == 0
  const int lin = blockIdx.x;
  const int s = (lin & 7) * (nwg >> 3) + (lin >> 3);
  const int m0 = (s & 31) * 128;          // 32 m-tiles
  const int n0 = (s >> 5) * 128;          // 12 n-tiles

  const int wm = w >> 1, wn = w & 1;
  const int K = 1024;

  f32x4 acc[4][4] = {};

  const int lr = l >> 3;               // row within 8-row chunk
  const int sc8 = 8 * ((l & 7) ^ lr);  // pre-swizzled elem col within 64-wide row

  auto stage = [&](int buf, int kt) {
    #pragma unroll
    for (int it = 0; it < 8; ++it) {
      int c = w * 8 + it;                       // 32 chunks: 16 As + 16 Bs
      if (c < 16) {
        int row = c * 8 + lr;
        gload_lds16(A + (size_t)(m0 + row) * K + kt + sc8, &As[buf][c * 512]);
      } else {
        int cc = c - 16;
        int row = cc * 8 + lr;
        gload_lds16(B + (size_t)(n0 + row) * K + kt + sc8, &Bs[buf][cc * 512]);
      }
    }
  };

  stage(0, 0);
  __syncthreads();
  int buf = 0;
  const int rswz = (lo16 & 7) << 4;    // read-side XOR (row&7)<<4; rows = *+lo16
  for (int kt = 0; kt < K; kt += 64) {
    if (kt + 64 < K) stage(buf ^ 1, kt + 64);
    #pragma unroll
    for (int kk = 0; kk < 2; ++kk) {
      bf16x8 af[4], bfr[4];
      const int colb = (kk * 64 + hi4 * 16) ^ rswz;   // swizzled byte col in 128B row
      #pragma unroll
      for (int f = 0; f < 4; ++f) {
        af[f]  = *(const bf16x8*)((const char*)&As[buf][0] + (wm * 64 + f * 16 + lo16) * 128 + colb);
        bfr[f] = *(const bf16x8*)((const char*)&Bs[buf][0] + (wn * 64 + f * 16 + lo16) * 128 + colb);
      }
      #pragma unroll
      for (int fm = 0; fm < 4; ++fm)
        #pragma unroll
        for (int fn = 0; fn < 4; ++fn)
          acc[fm][fn] = __builtin_amdgcn_mfma_f32_16x16x32_bf16(af[fm], bfr[fn], acc[fm][fn], 0, 0, 0);
    }
    __syncthreads();
    buf ^= 1;
  }

  if (n0 < 1280) {
    // q | k block: direct scatter (32B-granule coalesced)
    #pragma unroll
    for (int fm = 0; fm < 4; ++fm)
      #pragma unroll
      for (int fn = 0; fn < 4; ++fn) {
        f32x4 c = acc[fm][fn];
        const int gcol = n0 + wn * 64 + fn * 16 + lo16;
        const int rowb = m0 + wm * 64 + fm * 16 + hi4 * 4;
        float bias = (gcol < 1024) ? b0[gcol] : b1[gcol - 1024];
        #pragma unroll
        for (int j = 0; j < 4; ++j) {
          int m = rowb + j;
          u16 hb = f2bf(c[j] + bias);
          if (gcol < 1024) qh[((size_t)(gcol >> 7) * S_LEN + m) * HDIM + (gcol & 127)] = hb;
          else             kh[((size_t)((gcol - 1024) >> 7) * S_LEN + m) * HDIM + (gcol & 127)] = hb;
        }
      }
  } else {
    // v block: transpose via XOR-swizzled LDS, then coalesced 64B writes
    u16* tl = &As[0][0];     // 32KB (both As buffers)
    const int cc0 = n0 - 1280;
    #pragma unroll
    for (int fm = 0; fm < 4; ++fm)
      #pragma unroll
      for (int fn = 0; fn < 4; ++fn) {
        const int lcol = wn * 64 + fn * 16 + lo16;      // v channel 0..127
        const float bias = b2[cc0 + lcol];
        #pragma unroll
        for (int j = 0; j < 4; ++j) {
          const int lrow = wm * 64 + fm * 16 + hi4 * 4 + j;   // seq 0..127
          int a = lcol * 256 + ((lrow * 2) ^ ((lcol & 7) << 4));
          *(u16*)((char*)tl + a) = f2bf(acc[fm][fn][j] + bias);
        }
      }
    __syncthreads();
    const int ch = tid >> 1, half = tid & 1;
    const int swz = (ch & 7) << 4;
    u16* dst = vt + (size_t)(cc0 + ch) * S_LEN + m0 + half * 64;
    #pragma unroll
    for (int s8 = 0; s8 < 8; ++s8) {
      uint4 vv = *(const uint4*)((const char*)tl + ch * 256 + ((half * 128 + s8 * 16) ^ swz));
      *(uint4*)(dst + s8 * 8) = vv;
    }
  }
}

// ---------------- out-proj GEMM: 128x128 tile, 512 thr / 8 waves, 256 blocks (R14) ----------------
__global__ __launch_bounds__(512) void gemm_out(
    const u16* __restrict__ A, const u16* __restrict__ B,
    const float* __restrict__ b0, float* __restrict__ outf) {
  __shared__ __align__(16) u16 As[2][128 * 64];    // 2 x 16 KB
  __shared__ __align__(16) u16 Bs[2][128 * 64];    // 2 x 16 KB
  const int tid = threadIdx.x;
  const int w = tid >> 6, l = tid & 63;            // 8 waves
  const int lo16 = l & 15, hi4 = l >> 4;

  const int nwg = gridDim.x;              // 256, % 8 == 0
  const int lin = blockIdx.x;
  const int s = (lin & 7) * (nwg >> 3) + (lin >> 3);
  const int m0 = (s & 31) * 128;          // 32 m-tiles
  const int n0 = (s >> 5) * 128;          // 8 n-tiles

  const int wm = w >> 2, wn = w & 3;      // wave tile: rows wm*64, cols wn*32
  const int K = 1024;

  f32x4 acc[4][2] = {};

  const int lr = l >> 3;
  const int sc8 = 8 * ((l & 7) ^ lr);

  auto stage = [&](int buf, int kt) {
    #pragma unroll
    for (int it = 0; it < 4; ++it) {
      int c = w * 4 + it;                 // 32 chunks: 16 As + 16 Bs
      if (c < 16) {
        int row = c * 8 + lr;
        gload_lds16(A + (size_t)(m0 + row) * K + kt + sc8, &As[buf][c * 512]);
      } else {
        int cc = c - 16;
        int row = cc * 8 + lr;
        gload_lds16(B + (size_t)(n0 + row) * K + kt + sc8, &Bs[buf][cc * 512]);
      }
    }
  };

  stage(0, 0);
  __syncthreads();
  int buf = 0;
  const int rswz = (lo16 & 7) << 4;
  for (int kt = 0; kt < K; kt += 64) {
    if (kt + 64 < K) stage(buf ^ 1, kt + 64);
    #pragma unroll
    for (int kk = 0; kk < 2; ++kk) {
      bf16x8 af[4], bfr[2];
      const int colb = (kk * 64 + hi4 * 16) ^ rswz;
      #pragma unroll
      for (int f = 0; f < 4; ++f)
        af[f] = *(const bf16x8*)((const char*)&As[buf][0] + (wm * 64 + f * 16 + lo16) * 128 + colb);
      #pragma unroll
      for (int fn = 0; fn < 2; ++fn)
        bfr[fn] = *(const bf16x8*)((const char*)&Bs[buf][0] + (wn * 32 + fn * 16 + lo16) * 128 + colb);
      #pragma unroll
      for (int fm = 0; fm < 4; ++fm)
        #pragma unroll
        for (int fn = 0; fn < 2; ++fn)
          acc[fm][fn] = __builtin_amdgcn_mfma_f32_16x16x32_bf16(af[fm], bfr[fn], acc[fm][fn], 0, 0, 0);
    }
    __syncthreads();
    buf ^= 1;
  }

  #pragma unroll
  for (int fm = 0; fm < 4; ++fm)
    #pragma unroll
    for (int fn = 0; fn < 2; ++fn) {
      f32x4 c = acc[fm][fn];
      const int col  = n0 + wn * 32 + fn * 16 + lo16;
      const int rowb = m0 + wm * 64 + fm * 16 + hi4 * 4;
      float bias = b0[col];
      #pragma unroll
      for (int j = 0; j < 4; ++j)
        outf[(size_t)(rowb + j) * DM + col] = c[j] + bias;
    }
}

// ---------------- attention: burst-staged K/V, 3 barriers; Wo fold; T5 setprio ----------------
__global__ __launch_bounds__(512) void attn_kernel(
    const u16* __restrict__ qh, const u16* __restrict__ kh,
    const u16* __restrict__ vt, const float* __restrict__ sb_ptr,
    const float* __restrict__ wo, u16* __restrict__ wob,
    u16* __restrict__ ob) {
  __shared__ __align__(16) u16 kv_lds[5 * 8192];   // 80KB: K tiles, reused for V tiles
  __shared__ __align__(16) u16 p_lds[16384];       // 32KB
  const int lin = blockIdx.x;                    // 256 blocks
  const int sblk = (lin & 7) * 32 + (lin >> 3);  // XCD-chunked
  const int g  = sblk >> 7;                      // kv group 0..1
  const int qt = sblk & 127;                     // 0..127
  const int r0 = qt * 32;
  const int tid = threadIdx.x;
  const int w = tid >> 6, l = tid & 63;
  const int lo16 = l & 15, hi4 = l >> 4;
  const int h  = g * 4 + (w >> 1);               // head for this wave
  const int rw = r0 + (w & 1) * 16;              // first q-row for this wave
  const float sb = *sb_ptr;
  const float scale = 0.08838834764831845f;      // 1/sqrt(128)

  int lo = r0 - (WINSZ - 1); if (lo < 0) lo = 0;
  const int jt0 = lo >> 6;
  const int nt  = (r0 >> 6) - jt0 + 1;   // 1..5 (block-uniform)

  // ---- burst-stage all K tiles (issued first) ----
  #pragma unroll
  for (int t = 0; t < 5; ++t) {
    if (t < nt) {
      const int jt = jt0 + t;
      #pragma unroll
      for (int it = 0; it < 2; ++it) {
        int ch = w * 2 + it;                                   // 16 chunks/tile
        int r  = ch * 4 + (l >> 4);                            // K row 0..63
        int cb = ((l & 15) * 16) ^ ((r & 7) << 4);             // pre-swizzled col byte
        gload_lds16(kh + ((size_t)g * S_LEN + jt * 64 + r) * HDIM + (cb >> 1),
                    &kv_lds[t * 8192 + ch * 512]);
      }
    }
  }

  // Q fragments
  bf16x8 aq[4];
  {
    const u16* qbase = qh + ((size_t)h * S_LEN + rw + lo16) * HDIM + hi4 * 8;
    #pragma unroll
    for (int kk = 0; kk < 4; ++kk) aq[kk] = *(const bf16x8*)(qbase + kk * 32);
  }

  __syncthreads();                                 // barrier 1: K staged

  // ---- all QK^T (swapped operands: lane holds q=lo16 row) ----
  f32x4 sc[5][4];
  #pragma unroll
  for (int t = 0; t < 5; ++t)
    #pragma unroll
    for (int jn = 0; jn < 4; ++jn) sc[t][jn] = (f32x4){0.f, 0.f, 0.f, 0.f};
  __builtin_amdgcn_s_setprio(1);
  #pragma unroll
  for (int t = 0; t < 5; ++t) {
    if (t < nt) {
      #pragma unroll
      for (int jn = 0; jn < 4; ++jn) {
        const int R = jn * 16 + lo16;
        #pragma unroll
        for (int kk = 0; kk < 4; ++kk) {
          int addr = t * 16384 + R * 256 + ((kk * 64 + hi4 * 16) ^ ((R & 7) << 4));
          bf16x8 bk = *(const bf16x8*)((const char*)kv_lds + addr);
          sc[t][jn] = __builtin_amdgcn_mfma_f32_16x16x32_bf16(bk, aq[kk], sc[t][jn], 0, 0, 0);
        }
      }
    }
  }
  __builtin_amdgcn_s_setprio(0);

  // ---- scale + mask + row max (regs only) ----
  const int ig = rw + lo16;
  float pmax = -3e38f;
  #pragma unroll
  for (int t = 0; t < 5; ++t) {
    if (t < nt) {
      const int jt = jt0 + t;
      const bool edge = (jt * 64 + 63 > rw) || (jt * 64 < rw - 240);
      #pragma unroll
      for (int jn = 0; jn < 4; ++jn) {
        #pragma unroll
        for (int j = 0; j < 4; ++j) {
          float s2 = sc[t][jn][j] * scale;
          if (edge) {
            const int jg = jt * 64 + jn * 16 + hi4 * 4 + j;
            bool valid = (jg <= ig) && (jg > ig - WINSZ);
            s2 = valid ? s2 : -1e30f;
          }
          sc[t][jn][j] = s2;
          pmax = fmaxf(pmax, s2);
        }
      }
    }
  }
  pmax = fmaxf(pmax, __shfl_xor(pmax, 16, 64));
  pmax = fmaxf(pmax, __shfl_xor(pmax, 32, 64));
  const float m = fmaxf(pmax, sb);

  __syncthreads();                                 // barrier 2: all K reads done

  // ---- burst-issue all V tiles into the same region ----
  #pragma unroll
  for (int t = 0; t < 5; ++t) {
    if (t < nt) {
      const int jt = jt0 + t;
      #pragma unroll
      for (int it = 0; it < 2; ++it) {
        int ch = w * 2 + it;
        int r  = ch * 8 + (l >> 3);                            // V row (d) 0..127
        int cb = 16 * ((l & 7) ^ (l >> 3));                    // pre-swizzled col byte
        gload_lds16(vt + ((size_t)g * HDIM + r) * S_LEN + jt * 64 + (cb >> 1),
                    &kv_lds[t * 8192 + ch * 512]);
      }
    }
  }

  // ---- exp pass in registers (overlaps V burst) ----
  float rsum = 0.f;
  #pragma unroll
  for (int t = 0; t < 5; ++t) {
    if (t < nt) {
      #pragma unroll
      for (int jn = 0; jn < 4; ++jn) {
        #pragma unroll
        for (int j = 0; j < 4; ++j) {
          float p = __expf(sc[t][jn][j] - m);
          sc[t][jn][j] = p;
          rsum += p;
        }
      }
    }
  }
  rsum += __shfl_xor(rsum, 16, 64);
  rsum += __shfl_xor(rsum, 32, 64);

  __syncthreads();                                 // barrier 3: V staged

  // ---- fold: convert this block's Wo slice (no barrier after -> hides under PV) ----
  {
    const float* src = wo + (size_t)lin * 4096;
    u16* dst = wob + (size_t)lin * 4096;
    #pragma unroll
    for (int it = 0; it < 2; ++it) {
      int i = (it * 512 + tid) * 4;
      float4 v = *(const float4*)(src + i);
      ushort4 o;
      o.x = f2bf(v.x); o.y = f2bf(v.y); o.z = f2bf(v.z); o.w = f2bf(v.w);
      *(ushort4*)(dst + i) = o;
    }
  }

  // ---- all PV (P store -> 16 MFMA per tile; per-wave P slots, no barriers) ----
  f32x4 acc_o[8] = {};
  const int pswz = (lo16 & 7) << 4;
  __builtin_amdgcn_s_setprio(1);
  #pragma unroll
  for (int t = 0; t < 5; ++t) {
    if (t < nt) {
      char* pw = (char*)p_lds + (w * 2 + (t & 1)) * 2048 + lo16 * 128;
      #pragma unroll
      for (int jn = 0; jn < 4; ++jn) {
        uint2 pk;
        pk.x = (u32)f2bf(sc[t][jn][0]) | ((u32)f2bf(sc[t][jn][1]) << 16);
        pk.y = (u32)f2bf(sc[t][jn][2]) | ((u32)f2bf(sc[t][jn][3]) << 16);
        *(uint2*)(pw + ((jn * 32 + hi4 * 8) ^ pswz)) = pk;
      }
      #pragma unroll
      for (int kkp = 0; kkp < 2; ++kkp) {
        bf16x8 ap = *(const bf16x8*)((const char*)p_lds + (w * 2 + (t & 1)) * 2048
                                     + lo16 * 128 + ((kkp * 64 + hi4 * 16) ^ pswz));
        #pragma unroll
        for (int dn = 0; dn < 8; ++dn) {
          const int R = dn * 16 + lo16;
          int va = t * 16384 + R * 128 + ((kkp * 64 + hi4 * 16) ^ ((R & 7) << 4));
          bf16x8 bv = *(const bf16x8*)((const char*)kv_lds + va);
          acc_o[dn] = __builtin_amdgcn_mfma_f32_16x16x32_bf16(ap, bv, acc_o[dn], 0, 0, 0);
        }
      }
    }
  }
  __builtin_amdgcn_s_setprio(0);

  // ---- finalize ----
  const float invl = 1.f / (rsum + __expf(sb - m));
  float invj[4];
  #pragma unroll
  for (int j = 0; j < 4; ++j) invj[j] = __shfl(invl, hi4 * 4 + j, 64);
  #pragma unroll
  for (int dn = 0; dn < 8; ++dn)
    #pragma unroll
    for (int j = 0; j < 4; ++j)
      ob[(size_t)(rw + hi4 * 4 + j) * DM + h * HDIM + dn * 16 + lo16] = f2bf(acc_o[dn][j] * invj[j]);
}

extern "C" void kernel_launch(void* const* d_in, const int* in_sizes, int n_in,
                              void* d_out, int out_size, void* d_ws, size_t ws_size,
                              hipStream_t stream) {
  const float* x  = (const float*)d_in[0];
  const float* sb = (const float*)d_in[1];
  const float* wq = (const float*)d_in[2];
  const float* bq = (const float*)d_in[3];
  const float* wk = (const float*)d_in[4];
  const float* bk = (const float*)d_in[5];
  const float* wv = (const float*)d_in[6];
  const float* bv = (const float*)d_in[7];
  const float* wo = (const float*)d_in[8];
  const float* bo = (const float*)d_in[9];
  float* out = (float*)d_out;
  char* ws = (char*)d_ws;

  u16* xb    = (u16*)(ws + OFF_XB);
  u16* wqkvb = (u16*)(ws + OFF_WQKV);
  u16* wob   = (u16*)(ws + OFF_WO);
  u16* qh    = (u16*)(ws + OFF_QH);
  u16* kh    = (u16*)(ws + OFF_KH);
  u16* vt    = (u16*)(ws + OFF_VT);
  u16* ob    = (u16*)(ws + OFF_OB);

  // x|Wq|Wk|Wv: 1441792 float4s -> 5632 blocks
  prep_kernel<<<dim3(5632), dim3(256), 0, stream>>>(x, wq, wk, wv, xb, wqkvb);
  // qkv projection: M=4096, N=1536 -> 384 blocks, 128^2 tile, 256 thr
  gemm_qkv<<<dim3(384), dim3(256), 0, stream>>>(xb, wqkvb, bq, bk, bv, qh, kh, vt);
  // attention (+ Wo conversion fold): 256 blocks, 512 thr
  attn_kernel<<<dim3(256), dim3(512), 0, stream>>>(qh, kh, vt, sb, wo, wob, ob);
  // out projection: M=4096, N=1024 -> 256 blocks, 128^2 tile, 512 thr / 8 waves
  gemm_out<<<dim3(256), dim3(512), 0, stream>>>(ob, wob, bo, out);
}

// Round 17
// 62.655 us; speedup vs baseline: 1.0826x; 1.0485x over previous
//
#include <hip/hip_runtime.h>

#define S_LEN 4096
#define DM    1024
#define NH    8
#define NKV   2
#define HDIM  128
#define WINSZ 256

typedef unsigned short u16;
typedef unsigned int u32;
typedef float f32x4 __attribute__((ext_vector_type(4)));
typedef short bf16x8 __attribute__((ext_vector_type(8)));

// ---------- workspace layout (bytes) ----------
static const size_t OFF_XB   = 0;          // x bf16 [4096][1024]            8388608
static const size_t OFF_WQKV = 8388608;    // Wq|Wk|Wv bf16 [1536][1024]     3145728
static const size_t OFF_WO   = 11534336;   // Wo bf16 [1024][1024]           2097152
static const size_t OFF_QH   = 13631488;   // q bf16 [8][4096][128]          8388608
static const size_t OFF_KH   = 22020096;   // k bf16 [2][4096][128]          2097152
static const size_t OFF_VT   = 24117248;   // v^T bf16 [2][128][4096]        2097152
static const size_t OFF_OB   = 26214400;   // attn out bf16 [4096][1024]     8388608

__device__ __forceinline__ u16 f2bf(float f) {
  union { float f; unsigned int u; } v; v.f = f;
  unsigned int u = v.u;
  u += 0x7fffu + ((u >> 16) & 1u);   // RNE
  return (u16)(u >> 16);
}

__device__ __forceinline__ void gload_lds16(const u16* g, u16* l) {
  __builtin_amdgcn_global_load_lds((const __attribute__((address_space(1))) void*)g,
                                   (__attribute__((address_space(3))) void*)l, 16, 0, 0);
}

// ---------------- prep: x|Wq|Wk|Wv f32 -> bf16 (Wo folded into attn) ----------------
__global__ __launch_bounds__(256) void prep_kernel(
    const float* __restrict__ x,  const float* __restrict__ wq,
    const float* __restrict__ wk, const float* __restrict__ wv,
    u16* __restrict__ xb, u16* __restrict__ wqkvb) {
  int i = blockIdx.x * 256 + threadIdx.x;       // one float4 per thread
  const float* src; u16* dst;
  if (i < 1048576)      { src = x  + (size_t)i * 4;               dst = xb + (size_t)i * 4; }
  else if (i < 1310720) { int j = i - 1048576; src = wq + (size_t)j*4; dst = wqkvb + (size_t)j*4; }
  else if (i < 1376256) { int j = i - 1310720; src = wk + (size_t)j*4; dst = wqkvb + 1048576 + (size_t)j*4; }
  else                  { int j = i - 1376256; src = wv + (size_t)j*4; dst = wqkvb + 1310720 + (size_t)j*4; }
  float4 v = *(const float4*)src;
  ushort4 o;
  o.x = f2bf(v.x); o.y = f2bf(v.y); o.z = f2bf(v.z); o.w = f2bf(v.w);
  *(ushort4*)dst = o;
}

// ---------------- QKV GEMM, 128x128 tile, 384 blocks, 256 thr ----------------
// XCD map: each XCD owns a 4-m-tile x 12-n-tile rectangle -> per-XCD L2 working
// set = A 1MB + B 3MB (L2-resident) instead of A 8MB (thrash).
__global__ __launch_bounds__(256) void gemm_qkv(
    const u16* __restrict__ A, const u16* __restrict__ B,
    const float* __restrict__ b0, const float* __restrict__ b1, const float* __restrict__ b2,
    u16* __restrict__ qh, u16* __restrict__ kh, u16* __restrict__ vt) {
  __shared__ __align__(16) u16 As[2][128 * 64];    // 2 x 16 KB
  __shared__ __align__(16) u16 Bs[2][128 * 64];    // 2 x 16 KB
  const int tid = threadIdx.x;
  const int w = tid >> 6, l = tid & 63;
  const int lo16 = l & 15, hi4 = l >> 4;

  const int lin = blockIdx.x;             // 384 blocks
  const int xcd = lin & 7;
  const int sl  = lin >> 3;               // 0..47
  const int m0 = (xcd * 4 + (sl & 3)) * 128;    // 32 m-tiles: 4 per XCD
  const int n0 = (sl >> 2) * 128;               // 12 n-tiles

  const int wm = w >> 1, wn = w & 1;
  const int K = 1024;

  f32x4 acc[4][4] = {};

  const int lr = l >> 3;               // row within 8-row chunk
  const int sc8 = 8 * ((l & 7) ^ lr);  // pre-swizzled elem col within 64-wide row

  auto stage = [&](int buf, int kt) {
    #pragma unroll
    for (int it = 0; it < 8; ++it) {
      int c = w * 8 + it;                       // 32 chunks: 16 As + 16 Bs
      if (c < 16) {
        int row = c * 8 + lr;
        gload_lds16(A + (size_t)(m0 + row) * K + kt + sc8, &As[buf][c * 512]);
      } else {
        int cc = c - 16;
        int row = cc * 8 + lr;
        gload_lds16(B + (size_t)(n0 + row) * K + kt + sc8, &Bs[buf][cc * 512]);
      }
    }
  };

  stage(0, 0);
  __syncthreads();
  int buf = 0;
  const int rswz = (lo16 & 7) << 4;    // read-side XOR (row&7)<<4; rows = *+lo16
  for (int kt = 0; kt < K; kt += 64) {
    if (kt + 64 < K) stage(buf ^ 1, kt + 64);
    #pragma unroll
    for (int kk = 0; kk < 2; ++kk) {
      bf16x8 af[4], bfr[4];
      const int colb = (kk * 64 + hi4 * 16) ^ rswz;   // swizzled byte col in 128B row
      #pragma unroll
      for (int f = 0; f < 4; ++f) {
        af[f]  = *(const bf16x8*)((const char*)&As[buf][0] + (wm * 64 + f * 16 + lo16) * 128 + colb);
        bfr[f] = *(const bf16x8*)((const char*)&Bs[buf][0] + (wn * 64 + f * 16 + lo16) * 128 + colb);
      }
      #pragma unroll
      for (int fm = 0; fm < 4; ++fm)
        #pragma unroll
        for (int fn = 0; fn < 4; ++fn)
          acc[fm][fn] = __builtin_amdgcn_mfma_f32_16x16x32_bf16(af[fm], bfr[fn], acc[fm][fn], 0, 0, 0);
    }
    __syncthreads();
    buf ^= 1;
  }

  if (n0 < 1280) {
    // q | k block: direct scatter (32B-granule coalesced)
    #pragma unroll
    for (int fm = 0; fm < 4; ++fm)
      #pragma unroll
      for (int fn = 0; fn < 4; ++fn) {
        f32x4 c = acc[fm][fn];
        const int gcol = n0 + wn * 64 + fn * 16 + lo16;
        const int rowb = m0 + wm * 64 + fm * 16 + hi4 * 4;
        float bias = (gcol < 1024) ? b0[gcol] : b1[gcol - 1024];
        #pragma unroll
        for (int j = 0; j < 4; ++j) {
          int m = rowb + j;
          u16 hb = f2bf(c[j] + bias);
          if (gcol < 1024) qh[((size_t)(gcol >> 7) * S_LEN + m) * HDIM + (gcol & 127)] = hb;
          else             kh[((size_t)((gcol - 1024) >> 7) * S_LEN + m) * HDIM + (gcol & 127)] = hb;
        }
      }
  } else {
    // v block: transpose via XOR-swizzled LDS, then coalesced 64B writes
    u16* tl = &As[0][0];     // 32KB (both As buffers)
    const int cc0 = n0 - 1280;
    #pragma unroll
    for (int fm = 0; fm < 4; ++fm)
      #pragma unroll
      for (int fn = 0; fn < 4; ++fn) {
        const int lcol = wn * 64 + fn * 16 + lo16;      // v channel 0..127
        const float bias = b2[cc0 + lcol];
        #pragma unroll
        for (int j = 0; j < 4; ++j) {
          const int lrow = wm * 64 + fm * 16 + hi4 * 4 + j;   // seq 0..127
          int a = lcol * 256 + ((lrow * 2) ^ ((lcol & 7) << 4));
          *(u16*)((char*)tl + a) = f2bf(acc[fm][fn][j] + bias);
        }
      }
    __syncthreads();
    const int ch = tid >> 1, half = tid & 1;
    const int swz = (ch & 7) << 4;
    u16* dst = vt + (size_t)(cc0 + ch) * S_LEN + m0 + half * 64;
    #pragma unroll
    for (int s8 = 0; s8 < 8; ++s8) {
      uint4 vv = *(const uint4*)((const char*)tl + ch * 256 + ((half * 128 + s8 * 16) ^ swz));
      *(uint4*)(dst + s8 * 8) = vv;
    }
  }
}

// ---------------- out-proj GEMM: 128x128 tile, 512 thr / 8 waves, 256 blocks ----------------
// XCD map: 4-m-tile x 8-n-tile rectangle per XCD -> working set A 1MB + B 2MB.
__global__ __launch_bounds__(512) void gemm_out(
    const u16* __restrict__ A, const u16* __restrict__ B,
    const float* __restrict__ b0, float* __restrict__ outf) {
  __shared__ __align__(16) u16 As[2][128 * 64];    // 2 x 16 KB
  __shared__ __align__(16) u16 Bs[2][128 * 64];    // 2 x 16 KB
  const int tid = threadIdx.x;
  const int w = tid >> 6, l = tid & 63;            // 8 waves
  const int lo16 = l & 15, hi4 = l >> 4;

  const int lin = blockIdx.x;             // 256 blocks
  const int xcd = lin & 7;
  const int sl  = lin >> 3;               // 0..31
  const int m0 = (xcd * 4 + (sl & 3)) * 128;    // 32 m-tiles: 4 per XCD
  const int n0 = (sl >> 2) * 128;               // 8 n-tiles

  const int wm = w >> 2, wn = w & 3;      // wave tile: rows wm*64, cols wn*32
  const int K = 1024;

  f32x4 acc[4][2] = {};

  const int lr = l >> 3;
  const int sc8 = 8 * ((l & 7) ^ lr);

  auto stage = [&](int buf, int kt) {
    #pragma unroll
    for (int it = 0; it < 4; ++it) {
      int c = w * 4 + it;                 // 32 chunks: 16 As + 16 Bs
      if (c < 16) {
        int row = c * 8 + lr;
        gload_lds16(A + (size_t)(m0 + row) * K + kt + sc8, &As[buf][c * 512]);
      } else {
        int cc = c - 16;
        int row = cc * 8 + lr;
        gload_lds16(B + (size_t)(n0 + row) * K + kt + sc8, &Bs[buf][cc * 512]);
      }
    }
  };

  stage(0, 0);
  __syncthreads();
  int buf = 0;
  const int rswz = (lo16 & 7) << 4;
  for (int kt = 0; kt < K; kt += 64) {
    if (kt + 64 < K) stage(buf ^ 1, kt + 64);
    #pragma unroll
    for (int kk = 0; kk < 2; ++kk) {
      bf16x8 af[4], bfr[2];
      const int colb = (kk * 64 + hi4 * 16) ^ rswz;
      #pragma unroll
      for (int f = 0; f < 4; ++f)
        af[f] = *(const bf16x8*)((const char*)&As[buf][0] + (wm * 64 + f * 16 + lo16) * 128 + colb);
      #pragma unroll
      for (int fn = 0; fn < 2; ++fn)
        bfr[fn] = *(const bf16x8*)((const char*)&Bs[buf][0] + (wn * 32 + fn * 16 + lo16) * 128 + colb);
      #pragma unroll
      for (int fm = 0; fm < 4; ++fm)
        #pragma unroll
        for (int fn = 0; fn < 2; ++fn)
          acc[fm][fn] = __builtin_amdgcn_mfma_f32_16x16x32_bf16(af[fm], bfr[fn], acc[fm][fn], 0, 0, 0);
    }
    __syncthreads();
    buf ^= 1;
  }

  #pragma unroll
  for (int fm = 0; fm < 4; ++fm)
    #pragma unroll
    for (int fn = 0; fn < 2; ++fn) {
      f32x4 c = acc[fm][fn];
      const int col  = n0 + wn * 32 + fn * 16 + lo16;
      const int rowb = m0 + wm * 64 + fm * 16 + hi4 * 4;
      float bias = b0[col];
      #pragma unroll
      for (int j = 0; j < 4; ++j)
        outf[(size_t)(rowb + j) * DM + col] = c[j] + bias;
    }
}

// ---------------- attention: burst-staged K/V, 3 barriers; Wo fold (R14 exact) ----------------
__global__ __launch_bounds__(512) void attn_kernel(
    const u16* __restrict__ qh, const u16* __restrict__ kh,
    const u16* __restrict__ vt, const float* __restrict__ sb_ptr,
    const float* __restrict__ wo, u16* __restrict__ wob,
    u16* __restrict__ ob) {
  __shared__ __align__(16) u16 kv_lds[5 * 8192];   // 80KB: K tiles, reused for V tiles
  __shared__ __align__(16) u16 p_lds[16384];       // 32KB
  const int lin = blockIdx.x;                    // 256 blocks
  const int sblk = (lin & 7) * 32 + (lin >> 3);  // XCD-chunked
  const int g  = sblk >> 7;                      // kv group 0..1
  const int qt = sblk & 127;                     // 0..127
  const int r0 = qt * 32;
  const int tid = threadIdx.x;
  const int w = tid >> 6, l = tid & 63;
  const int lo16 = l & 15, hi4 = l >> 4;
  const int h  = g * 4 + (w >> 1);               // head for this wave
  const int rw = r0 + (w & 1) * 16;              // first q-row for this wave
  const float sb = *sb_ptr;
  const float scale = 0.08838834764831845f;      // 1/sqrt(128)

  int lo = r0 - (WINSZ - 1); if (lo < 0) lo = 0;
  const int jt0 = lo >> 6;
  const int nt  = (r0 >> 6) - jt0 + 1;   // 1..5 (block-uniform)

  // ---- burst-stage all K tiles (issued first) ----
  #pragma unroll
  for (int t = 0; t < 5; ++t) {
    if (t < nt) {
      const int jt = jt0 + t;
      #pragma unroll
      for (int it = 0; it < 2; ++it) {
        int ch = w * 2 + it;                                   // 16 chunks/tile
        int r  = ch * 4 + (l >> 4);                            // K row 0..63
        int cb = ((l & 15) * 16) ^ ((r & 7) << 4);             // pre-swizzled col byte
        gload_lds16(kh + ((size_t)g * S_LEN + jt * 64 + r) * HDIM + (cb >> 1),
                    &kv_lds[t * 8192 + ch * 512]);
      }
    }
  }

  // Q fragments
  bf16x8 aq[4];
  {
    const u16* qbase = qh + ((size_t)h * S_LEN + rw + lo16) * HDIM + hi4 * 8;
    #pragma unroll
    for (int kk = 0; kk < 4; ++kk) aq[kk] = *(const bf16x8*)(qbase + kk * 32);
  }

  __syncthreads();                                 // barrier 1: K staged

  // ---- all QK^T (swapped operands: lane holds q=lo16 row) ----
  f32x4 sc[5][4];
  #pragma unroll
  for (int t = 0; t < 5; ++t)
    #pragma unroll
    for (int jn = 0; jn < 4; ++jn) sc[t][jn] = (f32x4){0.f, 0.f, 0.f, 0.f};
  #pragma unroll
  for (int t = 0; t < 5; ++t) {
    if (t < nt) {
      #pragma unroll
      for (int jn = 0; jn < 4; ++jn) {
        const int R = jn * 16 + lo16;
        #pragma unroll
        for (int kk = 0; kk < 4; ++kk) {
          int addr = t * 16384 + R * 256 + ((kk * 64 + hi4 * 16) ^ ((R & 7) << 4));
          bf16x8 bk = *(const bf16x8*)((const char*)kv_lds + addr);
          sc[t][jn] = __builtin_amdgcn_mfma_f32_16x16x32_bf16(bk, aq[kk], sc[t][jn], 0, 0, 0);
        }
      }
    }
  }

  // ---- scale + mask + row max (regs only) ----
  const int ig = rw + lo16;
  float pmax = -3e38f;
  #pragma unroll
  for (int t = 0; t < 5; ++t) {
    if (t < nt) {
      const int jt = jt0 + t;
      const bool edge = (jt * 64 + 63 > rw) || (jt * 64 < rw - 240);
      #pragma unroll
      for (int jn = 0; jn < 4; ++jn) {
        #pragma unroll
        for (int j = 0; j < 4; ++j) {
          float s2 = sc[t][jn][j] * scale;
          if (edge) {
            const int jg = jt * 64 + jn * 16 + hi4 * 4 + j;
            bool valid = (jg <= ig) && (jg > ig - WINSZ);
            s2 = valid ? s2 : -1e30f;
          }
          sc[t][jn][j] = s2;
          pmax = fmaxf(pmax, s2);
        }
      }
    }
  }
  pmax = fmaxf(pmax, __shfl_xor(pmax, 16, 64));
  pmax = fmaxf(pmax, __shfl_xor(pmax, 32, 64));
  const float m = fmaxf(pmax, sb);

  __syncthreads();                                 // barrier 2: all K reads done

  // ---- burst-issue all V tiles into the same region ----
  #pragma unroll
  for (int t = 0; t < 5; ++t) {
    if (t < nt) {
      const int jt = jt0 + t;
      #pragma unroll
      for (int it = 0; it < 2; ++it) {
        int ch = w * 2 + it;
        int r  = ch * 8 + (l >> 3);                            // V row (d) 0..127
        int cb = 16 * ((l & 7) ^ (l >> 3));                    // pre-swizzled col byte
        gload_lds16(vt + ((size_t)g * HDIM + r) * S_LEN + jt * 64 + (cb >> 1),
                    &kv_lds[t * 8192 + ch * 512]);
      }
    }
  }

  // ---- exp pass in registers (overlaps V burst) ----
  float rsum = 0.f;
  #pragma unroll
  for (int t = 0; t < 5; ++t) {
    if (t < nt) {
      #pragma unroll
      for (int jn = 0; jn < 4; ++jn) {
        #pragma unroll
        for (int j = 0; j < 4; ++j) {
          float p = __expf(sc[t][jn][j] - m);
          sc[t][jn][j] = p;
          rsum += p;
        }
      }
    }
  }
  rsum += __shfl_xor(rsum, 16, 64);
  rsum += __shfl_xor(rsum, 32, 64);

  __syncthreads();                                 // barrier 3: V staged

  // ---- fold: convert this block's Wo slice (no barrier after -> hides under PV) ----
  {
    const float* src = wo + (size_t)lin * 4096;
    u16* dst = wob + (size_t)lin * 4096;
    #pragma unroll
    for (int it = 0; it < 2; ++it) {
      int i = (it * 512 + tid) * 4;
      float4 v = *(const float4*)(src + i);
      ushort4 o;
      o.x = f2bf(v.x); o.y = f2bf(v.y); o.z = f2bf(v.z); o.w = f2bf(v.w);
      *(ushort4*)(dst + i) = o;
    }
  }

  // ---- all PV (P store -> 16 MFMA per tile; per-wave P slots, no barriers) ----
  f32x4 acc_o[8] = {};
  const int pswz = (lo16 & 7) << 4;
  #pragma unroll
  for (int t = 0; t < 5; ++t) {
    if (t < nt) {
      char* pw = (char*)p_lds + (w * 2 + (t & 1)) * 2048 + lo16 * 128;
      #pragma unroll
      for (int jn = 0; jn < 4; ++jn) {
        uint2 pk;
        pk.x = (u32)f2bf(sc[t][jn][0]) | ((u32)f2bf(sc[t][jn][1]) << 16);
        pk.y = (u32)f2bf(sc[t][jn][2]) | ((u32)f2bf(sc[t][jn][3]) << 16);
        *(uint2*)(pw + ((jn * 32 + hi4 * 8) ^ pswz)) = pk;
      }
      #pragma unroll
      for (int kkp = 0; kkp < 2; ++kkp) {
        bf16x8 ap = *(const bf16x8*)((const char*)p_lds + (w * 2 + (t & 1)) * 2048
                                     + lo16 * 128 + ((kkp * 64 + hi4 * 16) ^ pswz));
        #pragma unroll
        for (int dn = 0; dn < 8; ++dn) {
          const int R = dn * 16 + lo16;
          int va = t * 16384 + R * 128 + ((kkp * 64 + hi4 * 16) ^ ((R & 7) << 4));
          bf16x8 bv = *(const bf16x8*)((const char*)kv_lds + va);
          acc_o[dn] = __builtin_amdgcn_mfma_f32_16x16x32_bf16(ap, bv, acc_o[dn], 0, 0, 0);
        }
      }
    }
  }

  // ---- finalize ----
  const float invl = 1.f / (rsum + __expf(sb - m));
  float invj[4];
  #pragma unroll
  for (int j = 0; j < 4; ++j) invj[j] = __shfl(invl, hi4 * 4 + j, 64);
  #pragma unroll
  for (int dn = 0; dn < 8; ++dn)
    #pragma unroll
    for (int j = 0; j < 4; ++j)
      ob[(size_t)(rw + hi4 * 4 + j) * DM + h * HDIM + dn * 16 + lo16] = f2bf(acc_o[dn][j] * invj[j]);
}

extern "C" void kernel_launch(void* const* d_in, const int* in_sizes, int n_in,
                              void* d_out, int out_size, void* d_ws, size_t ws_size,
                              hipStream_t stream) {
  const float* x  = (const float*)d_in[0];
  const float* sb = (const float*)d_in[1];
  const float* wq = (const float*)d_in[2];
  const float* bq = (const float*)d_in[3];
  const float* wk = (const float*)d_in[4];
  const float* bk = (const float*)d_in[5];
  const float* wv = (const float*)d_in[6];
  const float* bv = (const float*)d_in[7];
  const float* wo = (const float*)d_in[8];
  const float* bo = (const float*)d_in[9];
  float* out = (float*)d_out;
  char* ws = (char*)d_ws;

  u16* xb    = (u16*)(ws + OFF_XB);
  u16* wqkvb = (u16*)(ws + OFF_WQKV);
  u16* wob   = (u16*)(ws + OFF_WO);
  u16* qh    = (u16*)(ws + OFF_QH);
  u16* kh    = (u16*)(ws + OFF_KH);
  u16* vt    = (u16*)(ws + OFF_VT);
  u16* ob    = (u16*)(ws + OFF_OB);

  // x|Wq|Wk|Wv: 1441792 float4s -> 5632 blocks
  prep_kernel<<<dim3(5632), dim3(256), 0, stream>>>(x, wq, wk, wv, xb, wqkvb);
  // qkv projection: M=4096, N=1536 -> 384 blocks, 128^2 tile, 256 thr
  gemm_qkv<<<dim3(384), dim3(256), 0, stream>>>(xb, wqkvb, bq, bk, bv, qh, kh, vt);
  // attention (+ Wo conversion fold): 256 blocks, 512 thr
  attn_kernel<<<dim3(256), dim3(512), 0, stream>>>(qh, kh, vt, sb, wo, wob, ob);
  // out projection: M=4096, N=1024 -> 256 blocks, 128^2 tile, 512 thr / 8 waves
  gemm_out<<<dim3(256), dim3(512), 0, stream>>>(ob, wob, bo, out);
}

// Round 18
// 62.399 us; speedup vs baseline: 1.0870x; 1.0041x over previous
//
#include <hip/hip_runtime.h>

#define S_LEN 4096
#define DM    1024
#define NH    8
#define NKV   2
#define HDIM  128
#define WINSZ 256

typedef unsigned short u16;
typedef unsigned int u32;
typedef float f32x4 __attribute__((ext_vector_type(4)));
typedef short bf16x8 __attribute__((ext_vector_type(8)));

// ---------- workspace layout (bytes) ----------
static const size_t OFF_XB   = 0;          // x bf16 [4096][1024]            8388608
static const size_t OFF_WQKV = 8388608;    // Wq|Wk|Wv bf16 [1536][1024]     3145728
static const size_t OFF_WO   = 11534336;   // Wo bf16 [1024][1024]           2097152
static const size_t OFF_QH   = 13631488;   // q bf16 [8][4096][128]          8388608
static const size_t OFF_KH   = 22020096;   // k bf16 [2][4096][128]          2097152
static const size_t OFF_VT   = 24117248;   // v^T bf16 [2][128][4096]        2097152
static const size_t OFF_OB   = 26214400;   // attn out bf16 [4096][1024]     8388608

__device__ __forceinline__ u16 f2bf(float f) {
  union { float f; unsigned int u; } v; v.f = f;
  unsigned int u = v.u;
  u += 0x7fffu + ((u >> 16) & 1u);   // RNE
  return (u16)(u >> 16);
}

__device__ __forceinline__ void gload_lds16(const u16* g, u16* l) {
  __builtin_amdgcn_global_load_lds((const __attribute__((address_space(1))) void*)g,
                                   (__attribute__((address_space(3))) void*)l, 16, 0, 0);
}

// ---------------- prep: x|Wq|Wk|Wv f32 -> bf16 (Wo folded into attn) ----------------
__global__ __launch_bounds__(256) void prep_kernel(
    const float* __restrict__ x,  const float* __restrict__ wq,
    const float* __restrict__ wk, const float* __restrict__ wv,
    u16* __restrict__ xb, u16* __restrict__ wqkvb) {
  int i = blockIdx.x * 256 + threadIdx.x;       // one float4 per thread
  const float* src; u16* dst;
  if (i < 1048576)      { src = x  + (size_t)i * 4;               dst = xb + (size_t)i * 4; }
  else if (i < 1310720) { int j = i - 1048576; src = wq + (size_t)j*4; dst = wqkvb + (size_t)j*4; }
  else if (i < 1376256) { int j = i - 1310720; src = wk + (size_t)j*4; dst = wqkvb + 1048576 + (size_t)j*4; }
  else                  { int j = i - 1376256; src = wv + (size_t)j*4; dst = wqkvb + 1310720 + (size_t)j*4; }
  float4 v = *(const float4*)src;
  ushort4 o;
  o.x = f2bf(v.x); o.y = f2bf(v.y); o.z = f2bf(v.z); o.w = f2bf(v.w);
  *(ushort4*)dst = o;
}

// ---------------- QKV GEMM, 128x128 tile, 384 blocks, 256 thr (R17) ----------------
// XCD map: each XCD owns a 4-m-tile x 12-n-tile rectangle (rows [x*512, x*512+512)).
__global__ __launch_bounds__(256) void gemm_qkv(
    const u16* __restrict__ A, const u16* __restrict__ B,
    const float* __restrict__ b0, const float* __restrict__ b1, const float* __restrict__ b2,
    u16* __restrict__ qh, u16* __restrict__ kh, u16* __restrict__ vt) {
  __shared__ __align__(16) u16 As[2][128 * 64];    // 2 x 16 KB
  __shared__ __align__(16) u16 Bs[2][128 * 64];    // 2 x 16 KB
  const int tid = threadIdx.x;
  const int w = tid >> 6, l = tid & 63;
  const int lo16 = l & 15, hi4 = l >> 4;

  const int lin = blockIdx.x;             // 384 blocks
  const int xcd = lin & 7;
  const int sl  = lin >> 3;               // 0..47
  const int m0 = (xcd * 4 + (sl & 3)) * 128;    // 32 m-tiles: 4 per XCD
  const int n0 = (sl >> 2) * 128;               // 12 n-tiles

  const int wm = w >> 1, wn = w & 1;
  const int K = 1024;

  f32x4 acc[4][4] = {};

  const int lr = l >> 3;               // row within 8-row chunk
  const int sc8 = 8 * ((l & 7) ^ lr);  // pre-swizzled elem col within 64-wide row

  auto stage = [&](int buf, int kt) {
    #pragma unroll
    for (int it = 0; it < 8; ++it) {
      int c = w * 8 + it;                       // 32 chunks: 16 As + 16 Bs
      if (c < 16) {
        int row = c * 8 + lr;
        gload_lds16(A + (size_t)(m0 + row) * K + kt + sc8, &As[buf][c * 512]);
      } else {
        int cc = c - 16;
        int row = cc * 8 + lr;
        gload_lds16(B + (size_t)(n0 + row) * K + kt + sc8, &Bs[buf][cc * 512]);
      }
    }
  };

  stage(0, 0);
  __syncthreads();
  int buf = 0;
  const int rswz = (lo16 & 7) << 4;    // read-side XOR (row&7)<<4; rows = *+lo16
  for (int kt = 0; kt < K; kt += 64) {
    if (kt + 64 < K) stage(buf ^ 1, kt + 64);
    #pragma unroll
    for (int kk = 0; kk < 2; ++kk) {
      bf16x8 af[4], bfr[4];
      const int colb = (kk * 64 + hi4 * 16) ^ rswz;   // swizzled byte col in 128B row
      #pragma unroll
      for (int f = 0; f < 4; ++f) {
        af[f]  = *(const bf16x8*)((const char*)&As[buf][0] + (wm * 64 + f * 16 + lo16) * 128 + colb);
        bfr[f] = *(const bf16x8*)((const char*)&Bs[buf][0] + (wn * 64 + f * 16 + lo16) * 128 + colb);
      }
      #pragma unroll
      for (int fm = 0; fm < 4; ++fm)
        #pragma unroll
        for (int fn = 0; fn < 4; ++fn)
          acc[fm][fn] = __builtin_amdgcn_mfma_f32_16x16x32_bf16(af[fm], bfr[fn], acc[fm][fn], 0, 0, 0);
    }
    __syncthreads();
    buf ^= 1;
  }

  if (n0 < 1280) {
    // q | k block: direct scatter (32B-granule coalesced)
    #pragma unroll
    for (int fm = 0; fm < 4; ++fm)
      #pragma unroll
      for (int fn = 0; fn < 4; ++fn) {
        f32x4 c = acc[fm][fn];
        const int gcol = n0 + wn * 64 + fn * 16 + lo16;
        const int rowb = m0 + wm * 64 + fm * 16 + hi4 * 4;
        float bias = (gcol < 1024) ? b0[gcol] : b1[gcol - 1024];
        #pragma unroll
        for (int j = 0; j < 4; ++j) {
          int m = rowb + j;
          u16 hb = f2bf(c[j] + bias);
          if (gcol < 1024) qh[((size_t)(gcol >> 7) * S_LEN + m) * HDIM + (gcol & 127)] = hb;
          else             kh[((size_t)((gcol - 1024) >> 7) * S_LEN + m) * HDIM + (gcol & 127)] = hb;
        }
      }
  } else {
    // v block: transpose via XOR-swizzled LDS, then coalesced 64B writes
    u16* tl = &As[0][0];     // 32KB (both As buffers)
    const int cc0 = n0 - 1280;
    #pragma unroll
    for (int fm = 0; fm < 4; ++fm)
      #pragma unroll
      for (int fn = 0; fn < 4; ++fn) {
        const int lcol = wn * 64 + fn * 16 + lo16;      // v channel 0..127
        const float bias = b2[cc0 + lcol];
        #pragma unroll
        for (int j = 0; j < 4; ++j) {
          const int lrow = wm * 64 + fm * 16 + hi4 * 4 + j;   // seq 0..127
          int a = lcol * 256 + ((lrow * 2) ^ ((lcol & 7) << 4));
          *(u16*)((char*)tl + a) = f2bf(acc[fm][fn][j] + bias);
        }
      }
    __syncthreads();
    const int ch = tid >> 1, half = tid & 1;
    const int swz = (ch & 7) << 4;
    u16* dst = vt + (size_t)(cc0 + ch) * S_LEN + m0 + half * 64;
    #pragma unroll
    for (int s8 = 0; s8 < 8; ++s8) {
      uint4 vv = *(const uint4*)((const char*)tl + ch * 256 + ((half * 128 + s8 * 16) ^ swz));
      *(uint4*)(dst + s8 * 8) = vv;
    }
  }
}

// ---------------- out-proj GEMM: 128x128 tile, 512 thr / 8 waves, 256 blocks (R17) ----------------
__global__ __launch_bounds__(512) void gemm_out(
    const u16* __restrict__ A, const u16* __restrict__ B,
    const float* __restrict__ b0, float* __restrict__ outf) {
  __shared__ __align__(16) u16 As[2][128 * 64];    // 2 x 16 KB
  __shared__ __align__(16) u16 Bs[2][128 * 64];    // 2 x 16 KB
  const int tid = threadIdx.x;
  const int w = tid >> 6, l = tid & 63;            // 8 waves
  const int lo16 = l & 15, hi4 = l >> 4;

  const int lin = blockIdx.x;             // 256 blocks
  const int xcd = lin & 7;
  const int sl  = lin >> 3;               // 0..31
  const int m0 = (xcd * 4 + (sl & 3)) * 128;    // 32 m-tiles: 4 per XCD
  const int n0 = (sl >> 2) * 128;               // 8 n-tiles

  const int wm = w >> 2, wn = w & 3;      // wave tile: rows wm*64, cols wn*32
  const int K = 1024;

  f32x4 acc[4][2] = {};

  const int lr = l >> 3;
  const int sc8 = 8 * ((l & 7) ^ lr);

  auto stage = [&](int buf, int kt) {
    #pragma unroll
    for (int it = 0; it < 4; ++it) {
      int c = w * 4 + it;                 // 32 chunks: 16 As + 16 Bs
      if (c < 16) {
        int row = c * 8 + lr;
        gload_lds16(A + (size_t)(m0 + row) * K + kt + sc8, &As[buf][c * 512]);
      } else {
        int cc = c - 16;
        int row = cc * 8 + lr;
        gload_lds16(B + (size_t)(n0 + row) * K + kt + sc8, &Bs[buf][cc * 512]);
      }
    }
  };

  stage(0, 0);
  __syncthreads();
  int buf = 0;
  const int rswz = (lo16 & 7) << 4;
  for (int kt = 0; kt < K; kt += 64) {
    if (kt + 64 < K) stage(buf ^ 1, kt + 64);
    #pragma unroll
    for (int kk = 0; kk < 2; ++kk) {
      bf16x8 af[4], bfr[2];
      const int colb = (kk * 64 + hi4 * 16) ^ rswz;
      #pragma unroll
      for (int f = 0; f < 4; ++f)
        af[f] = *(const bf16x8*)((const char*)&As[buf][0] + (wm * 64 + f * 16 + lo16) * 128 + colb);
      #pragma unroll
      for (int fn = 0; fn < 2; ++fn)
        bfr[fn] = *(const bf16x8*)((const char*)&Bs[buf][0] + (wn * 32 + fn * 16 + lo16) * 128 + colb);
      #pragma unroll
      for (int fm = 0; fm < 4; ++fm)
        #pragma unroll
        for (int fn = 0; fn < 2; ++fn)
          acc[fm][fn] = __builtin_amdgcn_mfma_f32_16x16x32_bf16(af[fm], bfr[fn], acc[fm][fn], 0, 0, 0);
    }
    __syncthreads();
    buf ^= 1;
  }

  #pragma unroll
  for (int fm = 0; fm < 4; ++fm)
    #pragma unroll
    for (int fn = 0; fn < 2; ++fn) {
      f32x4 c = acc[fm][fn];
      const int col  = n0 + wn * 32 + fn * 16 + lo16;
      const int rowb = m0 + wm * 64 + fm * 16 + hi4 * 4;
      float bias = b0[col];
      #pragma unroll
      for (int j = 0; j < 4; ++j)
        outf[(size_t)(rowb + j) * DM + col] = c[j] + bias;
    }
}

// ---------------- attention: burst-staged K/V; XCD map aligned with GEMM row ownership ----------------
// XCD x handles qt in [x*16, x*16+16) for BOTH kv groups -> q/k/v reads and ob
// writes stay in the L2 that gemm_qkv populated / gemm_out will read.
__global__ __launch_bounds__(512) void attn_kernel(
    const u16* __restrict__ qh, const u16* __restrict__ kh,
    const u16* __restrict__ vt, const float* __restrict__ sb_ptr,
    const float* __restrict__ wo, u16* __restrict__ wob,
    u16* __restrict__ ob) {
  __shared__ __align__(16) u16 kv_lds[5 * 8192];   // 80KB: K tiles, reused for V tiles
  __shared__ __align__(16) u16 p_lds[16384];       // 32KB
  const int lin = blockIdx.x;                    // 256 blocks
  const int xcd  = lin & 7;
  const int slot = lin >> 3;                     // 0..31
  const int g  = slot >> 4;                      // kv group 0..1
  const int qt = xcd * 16 + (slot & 15);         // rows [xcd*512, xcd*512+512)
  const int r0 = qt * 32;
  const int tid = threadIdx.x;
  const int w = tid >> 6, l = tid & 63;
  const int lo16 = l & 15, hi4 = l >> 4;
  const int h  = g * 4 + (w >> 1);               // head for this wave
  const int rw = r0 + (w & 1) * 16;              // first q-row for this wave
  const float sb = *sb_ptr;
  const float scale = 0.08838834764831845f;      // 1/sqrt(128)

  int lo = r0 - (WINSZ - 1); if (lo < 0) lo = 0;
  const int jt0 = lo >> 6;
  const int nt  = (r0 >> 6) - jt0 + 1;   // 1..5 (block-uniform)

  // ---- burst-stage all K tiles (issued first) ----
  #pragma unroll
  for (int t = 0; t < 5; ++t) {
    if (t < nt) {
      const int jt = jt0 + t;
      #pragma unroll
      for (int it = 0; it < 2; ++it) {
        int ch = w * 2 + it;                                   // 16 chunks/tile
        int r  = ch * 4 + (l >> 4);                            // K row 0..63
        int cb = ((l & 15) * 16) ^ ((r & 7) << 4);             // pre-swizzled col byte
        gload_lds16(kh + ((size_t)g * S_LEN + jt * 64 + r) * HDIM + (cb >> 1),
                    &kv_lds[t * 8192 + ch * 512]);
      }
    }
  }

  // Q fragments
  bf16x8 aq[4];
  {
    const u16* qbase = qh + ((size_t)h * S_LEN + rw + lo16) * HDIM + hi4 * 8;
    #pragma unroll
    for (int kk = 0; kk < 4; ++kk) aq[kk] = *(const bf16x8*)(qbase + kk * 32);
  }

  __syncthreads();                                 // barrier 1: K staged

  // ---- all QK^T (swapped operands: lane holds q=lo16 row) ----
  f32x4 sc[5][4];
  #pragma unroll
  for (int t = 0; t < 5; ++t)
    #pragma unroll
    for (int jn = 0; jn < 4; ++jn) sc[t][jn] = (f32x4){0.f, 0.f, 0.f, 0.f};
  #pragma unroll
  for (int t = 0; t < 5; ++t) {
    if (t < nt) {
      #pragma unroll
      for (int jn = 0; jn < 4; ++jn) {
        const int R = jn * 16 + lo16;
        #pragma unroll
        for (int kk = 0; kk < 4; ++kk) {
          int addr = t * 16384 + R * 256 + ((kk * 64 + hi4 * 16) ^ ((R & 7) << 4));
          bf16x8 bk = *(const bf16x8*)((const char*)kv_lds + addr);
          sc[t][jn] = __builtin_amdgcn_mfma_f32_16x16x32_bf16(bk, aq[kk], sc[t][jn], 0, 0, 0);
        }
      }
    }
  }

  // ---- scale + mask + row max (regs only) ----
  const int ig = rw + lo16;
  float pmax = -3e38f;
  #pragma unroll
  for (int t = 0; t < 5; ++t) {
    if (t < nt) {
      const int jt = jt0 + t;
      const bool edge = (jt * 64 + 63 > rw) || (jt * 64 < rw - 240);
      #pragma unroll
      for (int jn = 0; jn < 4; ++jn) {
        #pragma unroll
        for (int j = 0; j < 4; ++j) {
          float s2 = sc[t][jn][j] * scale;
          if (edge) {
            const int jg = jt * 64 + jn * 16 + hi4 * 4 + j;
            bool valid = (jg <= ig) && (jg > ig - WINSZ);
            s2 = valid ? s2 : -1e30f;
          }
          sc[t][jn][j] = s2;
          pmax = fmaxf(pmax, s2);
        }
      }
    }
  }
  pmax = fmaxf(pmax, __shfl_xor(pmax, 16, 64));
  pmax = fmaxf(pmax, __shfl_xor(pmax, 32, 64));
  const float m = fmaxf(pmax, sb);

  __syncthreads();                                 // barrier 2: all K reads done

  // ---- burst-issue all V tiles into the same region ----
  #pragma unroll
  for (int t = 0; t < 5; ++t) {
    if (t < nt) {
      const int jt = jt0 + t;
      #pragma unroll
      for (int it = 0; it < 2; ++it) {
        int ch = w * 2 + it;
        int r  = ch * 8 + (l >> 3);                            // V row (d) 0..127
        int cb = 16 * ((l & 7) ^ (l >> 3));                    // pre-swizzled col byte
        gload_lds16(vt + ((size_t)g * HDIM + r) * S_LEN + jt * 64 + (cb >> 1),
                    &kv_lds[t * 8192 + ch * 512]);
      }
    }
  }

  // ---- exp pass in registers (overlaps V burst) ----
  float rsum = 0.f;
  #pragma unroll
  for (int t = 0; t < 5; ++t) {
    if (t < nt) {
      #pragma unroll
      for (int jn = 0; jn < 4; ++jn) {
        #pragma unroll
        for (int j = 0; j < 4; ++j) {
          float p = __expf(sc[t][jn][j] - m);
          sc[t][jn][j] = p;
          rsum += p;
        }
      }
    }
  }
  rsum += __shfl_xor(rsum, 16, 64);
  rsum += __shfl_xor(rsum, 32, 64);

  __syncthreads();                                 // barrier 3: V staged

  // ---- fold: convert this block's Wo slice (no barrier after -> hides under PV) ----
  {
    const float* src = wo + (size_t)lin * 4096;
    u16* dst = wob + (size_t)lin * 4096;
    #pragma unroll
    for (int it = 0; it < 2; ++it) {
      int i = (it * 512 + tid) * 4;
      float4 v = *(const float4*)(src + i);
      ushort4 o;
      o.x = f2bf(v.x); o.y = f2bf(v.y); o.z = f2bf(v.z); o.w = f2bf(v.w);
      *(ushort4*)(dst + i) = o;
    }
  }

  // ---- all PV (P store -> 16 MFMA per tile; per-wave P slots, no barriers) ----
  f32x4 acc_o[8] = {};
  const int pswz = (lo16 & 7) << 4;
  #pragma unroll
  for (int t = 0; t < 5; ++t) {
    if (t < nt) {
      char* pw = (char*)p_lds + (w * 2 + (t & 1)) * 2048 + lo16 * 128;
      #pragma unroll
      for (int jn = 0; jn < 4; ++jn) {
        uint2 pk;
        pk.x = (u32)f2bf(sc[t][jn][0]) | ((u32)f2bf(sc[t][jn][1]) << 16);
        pk.y = (u32)f2bf(sc[t][jn][2]) | ((u32)f2bf(sc[t][jn][3]) << 16);
        *(uint2*)(pw + ((jn * 32 + hi4 * 8) ^ pswz)) = pk;
      }
      #pragma unroll
      for (int kkp = 0; kkp < 2; ++kkp) {
        bf16x8 ap = *(const bf16x8*)((const char*)p_lds + (w * 2 + (t & 1)) * 2048
                                     + lo16 * 128 + ((kkp * 64 + hi4 * 16) ^ pswz));
        #pragma unroll
        for (int dn = 0; dn < 8; ++dn) {
          const int R = dn * 16 + lo16;
          int va = t * 16384 + R * 128 + ((kkp * 64 + hi4 * 16) ^ ((R & 7) << 4));
          bf16x8 bv = *(const bf16x8*)((const char*)kv_lds + va);
          acc_o[dn] = __builtin_amdgcn_mfma_f32_16x16x32_bf16(ap, bv, acc_o[dn], 0, 0, 0);
        }
      }
    }
  }

  // ---- finalize ----
  const float invl = 1.f / (rsum + __expf(sb - m));
  float invj[4];
  #pragma unroll
  for (int j = 0; j < 4; ++j) invj[j] = __shfl(invl, hi4 * 4 + j, 64);
  #pragma unroll
  for (int dn = 0; dn < 8; ++dn)
    #pragma unroll
    for (int j = 0; j < 4; ++j)
      ob[(size_t)(rw + hi4 * 4 + j) * DM + h * HDIM + dn * 16 + lo16] = f2bf(acc_o[dn][j] * invj[j]);
}

extern "C" void kernel_launch(void* const* d_in, const int* in_sizes, int n_in,
                              void* d_out, int out_size, void* d_ws, size_t ws_size,
                              hipStream_t stream) {
  const float* x  = (const float*)d_in[0];
  const float* sb = (const float*)d_in[1];
  const float* wq = (const float*)d_in[2];
  const float* bq = (const float*)d_in[3];
  const float* wk = (const float*)d_in[4];
  const float* bk = (const float*)d_in[5];
  const float* wv = (const float*)d_in[6];
  const float* bv = (const float*)d_in[7];
  const float* wo = (const float*)d_in[8];
  const float* bo = (const float*)d_in[9];
  float* out = (float*)d_out;
  char* ws = (char*)d_ws;

  u16* xb    = (u16*)(ws + OFF_XB);
  u16* wqkvb = (u16*)(ws + OFF_WQKV);
  u16* wob   = (u16*)(ws + OFF_WO);
  u16* qh    = (u16*)(ws + OFF_QH);
  u16* kh    = (u16*)(ws + OFF_KH);
  u16* vt    = (u16*)(ws + OFF_VT);
  u16* ob    = (u16*)(ws + OFF_OB);

  // x|Wq|Wk|Wv: 1441792 float4s -> 5632 blocks
  prep_kernel<<<dim3(5632), dim3(256), 0, stream>>>(x, wq, wk, wv, xb, wqkvb);
  // qkv projection: M=4096, N=1536 -> 384 blocks, 128^2 tile, 256 thr
  gemm_qkv<<<dim3(384), dim3(256), 0, stream>>>(xb, wqkvb, bq, bk, bv, qh, kh, vt);
  // attention (+ Wo conversion fold): 256 blocks, 512 thr
  attn_kernel<<<dim3(256), dim3(512), 0, stream>>>(qh, kh, vt, sb, wo, wob, ob);
  // out projection: M=4096, N=1024 -> 256 blocks, 128^2 tile, 512 thr / 8 waves
  gemm_out<<<dim3(256), dim3(512), 0, stream>>>(ob, wob, bo, out);
}